// Round 3
// baseline (335.942 us; speedup 1.0000x reference)
//
#include <hip/hip_runtime.h>

// LSTM: B=4096, T=1024, I=8, H=4. fp32.
// R7 (resubmit — previous round's bench failed on container acquisition, not
// on the kernel): rcp-free activations. R6 post-mortem: removing VALU levels
// from the scan chain did nothing (+3.5%) -> chain is transcendental-latency
// bound (fit: 9 VALU + 4 trans levels = 277 cyc/step -> t ~= 55 cyc).
// R7 removes BOTH v_rcp levels from the cycle: every activation here is
// 1/(1+exp2(z)); with e = exp2(-|z|) in (0,1], 1/(1+e) is approximated by a
// deg-8 polynomial in u = 1-2e (Chebyshev truncation of 2/(3-u), closed-form
// coeffs sqrt(2)*(3-2*sqrt(2))^n, max err 2.3e-7 ~= v_rcp's own error).
// Branchless sign: sig = P * (z>0 ? e : 1). Chain/step becomes
// 2 ex2 + ~19 FMA levels (was 4 trans + 9 VALU).
// Producer unchanged (same pre-scaled exp2-domain pre-acts).
// Lane layout: 4 lanes/batch elem; lane j owns hidden j, gate rows
// {j,4+j,8+j,12+j} (PyTorch i,f,g,o). Broadcast via DPP quad_perm.

#define TT 1024
#define II 8
#define CHUNK 32
#define NCHUNK (TT / CHUNK)  // 32
#define ROW (CHUNK * II)     // 256 floats x per stream per chunk
#define SPAD 4

#define L2E 1.4426950408889634f
#define SIG_SCALE (-L2E)       // i,f,o rows
#define G_SCALE (2.0f * L2E)   // g row

// P(u) ~= 1/(1+e), u = 1-2e, e in [0,1]. Chebyshev of 2/(3-u), deg 8.
#define PC0 0.66666669f
#define PC1 0.22222064f
#define PC2 0.074072687f
#define PC3 0.024712137f
#define PC4 0.0082420549f
#define PC5 0.0026708711f
#define PC6 0.00088259397f
#define PC7 0.00039615575f
#define PC8 0.00013594036f

typedef float v2f __attribute__((ext_vector_type(2)));

template <int CTRL>
__device__ __forceinline__ float dppf(float v) {
  return __int_as_float(
      __builtin_amdgcn_mov_dpp(__float_as_int(v), CTRL, 0xF, 0xF, true));
}

__device__ __forceinline__ float ex2(float x) {
  return __builtin_amdgcn_exp2f(x);
}
__device__ __forceinline__ float rcp(float x) {
  return __builtin_amdgcn_rcpf(x);
}

// deg-8 Estrin, depth 5 from u.
__device__ __forceinline__ float poly1e(float u) {
  const float u2 = u * u, u4 = u2 * u2;
  const float q0 = fmaf(PC1, u, PC0);
  const float q1 = fmaf(PC3, u, PC2);
  const float q2 = fmaf(PC5, u, PC4);
  const float q3 = fmaf(PC7, u, PC6);
  const float r0 = fmaf(q1, u2, q0);
  const float r1 = fmaf(q3, u2, q2);
  return fmaf(u4, fmaf(u4, PC8, r1), r0);
}

__device__ __forceinline__ v2f poly2e(v2f u) {
  const v2f u2 = u * u, u4 = u2 * u2;
  v2f q0 = __builtin_elementwise_fma(v2f{PC1, PC1}, u, v2f{PC0, PC0});
  v2f q1 = __builtin_elementwise_fma(v2f{PC3, PC3}, u, v2f{PC2, PC2});
  v2f q2 = __builtin_elementwise_fma(v2f{PC5, PC5}, u, v2f{PC4, PC4});
  v2f q3 = __builtin_elementwise_fma(v2f{PC7, PC7}, u, v2f{PC6, PC6});
  v2f r0 = __builtin_elementwise_fma(q1, u2, q0);
  v2f r1 = __builtin_elementwise_fma(q3, u2, q2);
  v2f s = __builtin_elementwise_fma(v2f{PC8, PC8}, u4, r1);
  return __builtin_elementwise_fma(u4, s, r0);
}

#define GLOAD_LDS16(gp, lp)                                   \
  __builtin_amdgcn_global_load_lds(                           \
      (const __attribute__((address_space(1))) void*)(gp),    \
      (__attribute__((address_space(3))) void*)(lp), 16, 0, 0)

__global__ __launch_bounds__(128, 1) void lstm_fused(
    const float* __restrict__ x, const float* __restrict__ W_ih,
    const float* __restrict__ W_hh, const float* __restrict__ b_ih,
    const float* __restrict__ b_hh, const float* __restrict__ fc_w,
    const float* __restrict__ fc_b, float* __restrict__ out, int B) {
  const int tid = threadIdx.x;
  const int wave = tid >> 6;
  const int lane = tid & 63;
  const int j = lane & 3;
  const int grp = lane >> 2;
  const int b = blockIdx.x * 16 + grp;

  __shared__ float xs0[16][ROW + SPAD];
  __shared__ float xs1[16][ROW + SPAD];
  // pre-act ring: [step][stream][j*4 + gate] — lane rw one contiguous float4;
  // wave touches 1KB stride-1 per step (2-way bank alias = free).
  __shared__ float pa0[CHUNK][16][16];
  __shared__ float pa1[CHUNK][16][16];

  if (wave == 0) {
    // ---------------- producer ----------------
    v2f wih01[II], wih23[II];
    v2f bias01, bias23;
#pragma unroll
    for (int k = 0; k < II; ++k) {
      wih01[k] = v2f{SIG_SCALE * W_ih[(0 * 4 + j) * II + k],
                     SIG_SCALE * W_ih[(1 * 4 + j) * II + k]};
      wih23[k] = v2f{G_SCALE * W_ih[(2 * 4 + j) * II + k],
                     SIG_SCALE * W_ih[(3 * 4 + j) * II + k]};
    }
    bias01 = v2f{SIG_SCALE * (b_ih[0 * 4 + j] + b_hh[0 * 4 + j]),
                 SIG_SCALE * (b_ih[1 * 4 + j] + b_hh[1 * 4 + j])};
    bias23 = v2f{G_SCALE * (b_ih[2 * 4 + j] + b_hh[2 * 4 + j]),
                 SIG_SCALE * (b_ih[3 * 4 + j] + b_hh[3 * 4 + j])};

    const size_t blockBase = (size_t)blockIdx.x * 16;

    auto issue = [&](float(*xs)[ROW + SPAD], int t0) {
#pragma unroll
      for (int s = 0; s < 16; ++s) {
        const float* gp =
            x + (blockBase + s) * (TT * II) + (size_t)t0 * II + lane * 4;
        GLOAD_LDS16(gp, &xs[s][0]);
      }
    };

    auto produce = [&](float(*pa)[16][16], const float(*xs)[ROW + SPAD]) {
      const float* row = &xs[grp][0];
#pragma unroll 8
      for (int u = 0; u < CHUNK; ++u) {
        const float4 xa = *(const float4*)(row + u * 8);
        const float4 xb = *(const float4*)(row + u * 8 + 4);
        v2f a01 = bias01, a23 = bias23;
#define XFMA(k, val)                                    \
  {                                                     \
    v2f xv = v2f{(val), (val)};                         \
    a01 = __builtin_elementwise_fma(wih01[k], xv, a01); \
    a23 = __builtin_elementwise_fma(wih23[k], xv, a23); \
  }
        XFMA(0, xa.x) XFMA(1, xa.y) XFMA(2, xa.z) XFMA(3, xa.w)
        XFMA(4, xb.x) XFMA(5, xb.y) XFMA(6, xb.z) XFMA(7, xb.w)
#undef XFMA
        *(float4*)&pa[u][grp][j * 4] = float4{a01.x, a01.y, a23.x, a23.y};
      }
    };

    issue(xs0, 0);
    issue(xs1, CHUNK);
    produce(pa0, xs0);
    __syncthreads();

    for (int ck = 0; ck < NCHUNK; ++ck) {
      if (ck + 1 < NCHUNK)
        produce(((ck + 1) & 1) ? pa1 : pa0, ((ck + 1) & 1) ? xs1 : xs0);
      if (ck + 2 < NCHUNK) issue((ck & 1) ? xs1 : xs0, (ck + 2) * CHUNK);
      __syncthreads();
    }
  } else {
    // ---------------- consumer (serial scan) ----------------
    // W_hh rows pre-scaled to match the producer's pre-act domain.
    v2f whh01[4], whh23[4];
#pragma unroll
    for (int k = 0; k < 4; ++k) {
      whh01[k] = v2f{SIG_SCALE * W_hh[(0 * 4 + j) * 4 + k],
                     SIG_SCALE * W_hh[(1 * 4 + j) * 4 + k]};
      whh23[k] = v2f{G_SCALE * W_hh[(2 * 4 + j) * 4 + k],
                     SIG_SCALE * W_hh[(3 * 4 + j) * 4 + k]};
    }
    // Carried state: c2 = 2*log2e*c, rc = (1-tanh(c))/2, og = sig(o).
    // og=0 makes the first step's feedback exactly zero regardless of rc.
    float c2 = 0.0f, rc = 0.25f, og = 0.0f;

    auto step = [&](float4 g) {
      // ---- feedback from carried (rc, og): h_k = og_k * (1 - 2*rc_k) ----
      const float s = fmaf(rc, -2.0f, 1.0f);  // tanh(c), 1 fma off rc
      const float s0 = dppf<0x00>(s), s1 = dppf<0x55>(s);
      const float s2 = dppf<0xAA>(s), s3 = dppf<0xFF>(s);
      const float o0 = dppf<0x00>(og), o1 = dppf<0x55>(og);
      const float o2 = dppf<0xAA>(og), o3 = dppf<0xFF>(og);
      // m_k = W[:,k]*og_k — og is ready well before rc: off-chain.
      const v2f m01_0 = whh01[0] * o0, m01_1 = whh01[1] * o1;
      const v2f m01_2 = whh01[2] * o2, m01_3 = whh01[3] * o3;
      const v2f m23_0 = whh23[0] * o0, m23_1 = whh23[1] * o1;
      const v2f m23_2 = whh23[2] * o2, m23_3 = whh23[3] * o3;
      // tree accumulate: depth 3 (fma,fma || mul,fma; add)
      v2f u01 = __builtin_elementwise_fma(m01_0, v2f{s0, s0}, v2f{g.x, g.y});
      u01 = __builtin_elementwise_fma(m01_1, v2f{s1, s1}, u01);
      v2f v01 = m01_2 * s2;
      v01 = __builtin_elementwise_fma(m01_3, v2f{s3, s3}, v01);
      const v2f a01 = u01 + v01;  // {i', f'} (scaled -log2e)
      v2f u23 = __builtin_elementwise_fma(m23_0, v2f{s0, s0}, v2f{g.z, g.w});
      u23 = __builtin_elementwise_fma(m23_1, v2f{s1, s1}, u23);
      v2f v23 = m23_2 * s2;
      v23 = __builtin_elementwise_fma(m23_3, v2f{s3, s3}, v23);
      const v2f a23 = u23 + v23;  // {g' (2log2e), o' (-log2e)}
      // ---- activations: 1/(1+exp2(z)) via rcp-free polynomial ----
      const float ei = ex2(-__builtin_fabsf(a01.x));
      const float ef = ex2(-__builtin_fabsf(a01.y));
      const float eg = ex2(-__builtin_fabsf(a23.x));
      const float eo = ex2(-__builtin_fabsf(a23.y));
      const v2f e01 = v2f{ei, ef};
      const v2f e23 = v2f{eg, eo};
      const v2f uu01 =
          __builtin_elementwise_fma(v2f{-2.f, -2.f}, e01, v2f{1.f, 1.f});
      const v2f uu23 =
          __builtin_elementwise_fma(v2f{-2.f, -2.f}, e23, v2f{1.f, 1.f});
      const v2f P01 = poly2e(uu01);
      const v2f P23 = poly2e(uu23);
      const float ig = P01.x * (a01.x > 0.f ? ei : 1.f);  // sig(i)
      const float fg = P01.y * (a01.y > 0.f ? ef : 1.f);  // sig(f)
      const float rg = P23.x * (a23.x > 0.f ? eg : 1.f);  // (1-tanh(g))/2
      og = P23.y * (a23.y > 0.f ? eo : 1.f);              // sig(o)
      const float gg2 = fmaf(rg, -2.0f * G_SCALE, G_SCALE);  // 2log2e*tanh(g)
      const float fc = fg * c2;  // overlaps gg2's fma
      c2 = fmaf(ig, gg2, fc);
      // ---- tanh(c): same rcp-free path ----
      const float ec = ex2(-__builtin_fabsf(c2));
      const float uc = fmaf(-2.f, ec, 1.f);
      const float Pc = poly1e(uc);
      rc = Pc * (c2 > 0.f ? ec : 1.f);  // (1-tanh(c))/2
    };

    __syncthreads();

    for (int ck = 0; ck < NCHUNK; ++ck) {
      const float(*pa)[16][16] = (ck & 1) ? pa1 : pa0;
      const float* base = &pa[0][grp][j * 4];

      float4 ra[8], rb[8];
#define LOADB(r, u0)                                                \
  {                                                                 \
    _Pragma("unroll") for (int k = 0; k < 8; ++k) (r)[k] =          \
        *(const float4*)(base + (u0 + k) * 256);                    \
  }
#define COMP8(r)                                   \
  { _Pragma("unroll") for (int k = 0; k < 8; ++k) step((r)[k]); }

      LOADB(ra, 0)
      LOADB(rb, 8)
      COMP8(ra)
      LOADB(ra, 16)
      COMP8(rb)
      LOADB(rb, 24)
      COMP8(ra)
      COMP8(rb)
#undef LOADB
#undef COMP8
      __syncthreads();
    }

    // final FC: out[b] = sum_j h_j * fc_w[j] + fc_b,  h = og * tanh(c)
    const float h = og * fmaf(rc, -2.0f, 1.0f);
    float v = h * fc_w[j];
    v += dppf<0xB1>(v);  // quad_perm [1,0,3,2]
    v += dppf<0x4E>(v);  // quad_perm [2,3,0,1]
    if (j == 0 && b < B) out[b] = v + fc_b[0];
  }
}

extern "C" void kernel_launch(void* const* d_in, const int* in_sizes, int n_in,
                              void* d_out, int out_size, void* d_ws,
                              size_t ws_size, hipStream_t stream) {
  const float* x = (const float*)d_in[0];
  const float* W_ih = (const float*)d_in[1];
  const float* W_hh = (const float*)d_in[2];
  const float* b_ih = (const float*)d_in[3];
  const float* b_hh = (const float*)d_in[4];
  const float* fc_w = (const float*)d_in[5];
  const float* fc_b = (const float*)d_in[6];
  float* out = (float*)d_out;

  const int B = in_sizes[0] / (TT * II);
  const int nblocks = (B + 15) / 16;
  lstm_fused<<<nblocks, 128, 0, stream>>>(x, W_ih, W_hh, b_ih, b_hh, fc_w,
                                          fc_b, out, B);
}

// Round 4
// 260.633 us; speedup vs baseline: 1.2889x; 1.2889x over previous
//
#include <hip/hip_runtime.h>

// LSTM: B=4096, T=1024, I=8, H=4. fp32.
// R8: revert to R5 (118us/dispatch, best measured) + two minimal chain trims.
// R7 post-mortem: poly activations = +65% and absmax 9.8e-4 (error amplified
// ~4000x over 1024 steps) -> chain cost ~17 cyc per dependent level of ANY
// type (solo-wave dependent-issue turnaround); keep hw ex2/rcp activations.
// R6 post-mortem: its level cut was eaten by the scheduler serializing the
// og-broadcast chain into the rc chain -> make NO broadcast changes.
// R8 = R5 with exactly two edits in the consumer step (16 -> 14 levels):
//  (i)  W_hh feedback as depth-3 tree after h-bcast (was 4 chained fma):
//       ((g + w0h0) + w1h1) + (w2h2 fma w3h3). +2 v2f instrs, -1 level.
//  (ii) c-update rebalanced: c2 = fma(ig, gg2, fg*c2) - the fg*c2 mul
//       overlaps gg2's fma (was fma(fg, c2, ig*gg2), one level deeper).
// Lane layout: 4 lanes/batch elem; lane j owns hidden j, gate rows
// {j,4+j,8+j,12+j} (PyTorch i,f,g,o). h-broadcast via DPP quad_perm.

#define TT 1024
#define II 8
#define CHUNK 32
#define NCHUNK (TT / CHUNK)  // 32
#define ROW (CHUNK * II)     // 256 floats x per stream per chunk
#define SPAD 4

#define L2E 1.4426950408889634f
#define SIG_SCALE (-L2E)       // i,f,o rows
#define G_SCALE (2.0f * L2E)   // g row

typedef float v2f __attribute__((ext_vector_type(2)));

template <int CTRL>
__device__ __forceinline__ float dppf(float v) {
  return __int_as_float(
      __builtin_amdgcn_mov_dpp(__float_as_int(v), CTRL, 0xF, 0xF, true));
}

__device__ __forceinline__ float ex2(float x) {
  return __builtin_amdgcn_exp2f(x);
}
__device__ __forceinline__ float rcp(float x) {
  return __builtin_amdgcn_rcpf(x);
}

#define GLOAD_LDS16(gp, lp)                                   \
  __builtin_amdgcn_global_load_lds(                           \
      (const __attribute__((address_space(1))) void*)(gp),    \
      (__attribute__((address_space(3))) void*)(lp), 16, 0, 0)

__global__ __launch_bounds__(128, 1) void lstm_fused(
    const float* __restrict__ x, const float* __restrict__ W_ih,
    const float* __restrict__ W_hh, const float* __restrict__ b_ih,
    const float* __restrict__ b_hh, const float* __restrict__ fc_w,
    const float* __restrict__ fc_b, float* __restrict__ out, int B) {
  const int tid = threadIdx.x;
  const int wave = tid >> 6;
  const int lane = tid & 63;
  const int j = lane & 3;
  const int grp = lane >> 2;
  const int b = blockIdx.x * 16 + grp;

  __shared__ float xs0[16][ROW + SPAD];
  __shared__ float xs1[16][ROW + SPAD];
  // pre-act ring: [step][stream][j*4 + gate] — lane rw one contiguous float4;
  // wave touches 1KB stride-1 per step (2-way bank alias = free).
  __shared__ float pa0[CHUNK][16][16];
  __shared__ float pa1[CHUNK][16][16];

  if (wave == 0) {
    // ---------------- producer ----------------
    v2f wih01[II], wih23[II];
    v2f bias01, bias23;
#pragma unroll
    for (int k = 0; k < II; ++k) {
      wih01[k] = v2f{SIG_SCALE * W_ih[(0 * 4 + j) * II + k],
                     SIG_SCALE * W_ih[(1 * 4 + j) * II + k]};
      wih23[k] = v2f{G_SCALE * W_ih[(2 * 4 + j) * II + k],
                     SIG_SCALE * W_ih[(3 * 4 + j) * II + k]};
    }
    bias01 = v2f{SIG_SCALE * (b_ih[0 * 4 + j] + b_hh[0 * 4 + j]),
                 SIG_SCALE * (b_ih[1 * 4 + j] + b_hh[1 * 4 + j])};
    bias23 = v2f{G_SCALE * (b_ih[2 * 4 + j] + b_hh[2 * 4 + j]),
                 SIG_SCALE * (b_ih[3 * 4 + j] + b_hh[3 * 4 + j])};

    const size_t blockBase = (size_t)blockIdx.x * 16;

    auto issue = [&](float(*xs)[ROW + SPAD], int t0) {
#pragma unroll
      for (int s = 0; s < 16; ++s) {
        const float* gp =
            x + (blockBase + s) * (TT * II) + (size_t)t0 * II + lane * 4;
        GLOAD_LDS16(gp, &xs[s][0]);
      }
    };

    auto produce = [&](float(*pa)[16][16], const float(*xs)[ROW + SPAD]) {
      const float* row = &xs[grp][0];
#pragma unroll 8
      for (int u = 0; u < CHUNK; ++u) {
        const float4 xa = *(const float4*)(row + u * 8);
        const float4 xb = *(const float4*)(row + u * 8 + 4);
        v2f a01 = bias01, a23 = bias23;
#define XFMA(k, val)                                    \
  {                                                     \
    v2f xv = v2f{(val), (val)};                         \
    a01 = __builtin_elementwise_fma(wih01[k], xv, a01); \
    a23 = __builtin_elementwise_fma(wih23[k], xv, a23); \
  }
        XFMA(0, xa.x) XFMA(1, xa.y) XFMA(2, xa.z) XFMA(3, xa.w)
        XFMA(4, xb.x) XFMA(5, xb.y) XFMA(6, xb.z) XFMA(7, xb.w)
#undef XFMA
        *(float4*)&pa[u][grp][j * 4] = float4{a01.x, a01.y, a23.x, a23.y};
      }
    };

    issue(xs0, 0);
    issue(xs1, CHUNK);
    produce(pa0, xs0);
    __syncthreads();

    for (int ck = 0; ck < NCHUNK; ++ck) {
      if (ck + 1 < NCHUNK)
        produce(((ck + 1) & 1) ? pa1 : pa0, ((ck + 1) & 1) ? xs1 : xs0);
      if (ck + 2 < NCHUNK) issue((ck & 1) ? xs1 : xs0, (ck + 2) * CHUNK);
      __syncthreads();
    }
  } else {
    // ---------------- consumer (serial scan) ----------------
    // W_hh rows pre-scaled to match the producer's pre-act domain.
    v2f whh01[4], whh23[4];
#pragma unroll
    for (int k = 0; k < 4; ++k) {
      whh01[k] = v2f{SIG_SCALE * W_hh[(0 * 4 + j) * 4 + k],
                     SIG_SCALE * W_hh[(1 * 4 + j) * 4 + k]};
      whh23[k] = v2f{G_SCALE * W_hh[(2 * 4 + j) * 4 + k],
                     SIG_SCALE * W_hh[(3 * 4 + j) * 4 + k]};
    }
    float h = 0.0f, c2 = 0.0f;  // c2 = 2*log2e * c

    auto step = [&](float4 g) {
      const float h0 = dppf<0x00>(h);
      const float h1 = dppf<0x55>(h);
      const float h2 = dppf<0xAA>(h);
      const float h3 = dppf<0xFF>(h);
      // (i) depth-3 tree after bcast: ((g+w0h0)+w1h1) + (w2h2 fma w3h3)
      v2f t01 =
          __builtin_elementwise_fma(whh01[0], v2f{h0, h0}, v2f{g.x, g.y});
      t01 = __builtin_elementwise_fma(whh01[1], v2f{h1, h1}, t01);
      v2f u01 = whh01[2] * v2f{h2, h2};
      u01 = __builtin_elementwise_fma(whh01[3], v2f{h3, h3}, u01);
      const v2f a01 = t01 + u01;  // {i', f'} (scaled -log2e)
      v2f t23 =
          __builtin_elementwise_fma(whh23[0], v2f{h0, h0}, v2f{g.z, g.w});
      t23 = __builtin_elementwise_fma(whh23[1], v2f{h1, h1}, t23);
      v2f u23 = whh23[2] * v2f{h2, h2};
      u23 = __builtin_elementwise_fma(whh23[3], v2f{h3, h3}, u23);
      const v2f a23 = t23 + u23;  // {g' (2log2e), o' (-log2e)}
      // activations (exp2 domain, hw ex2+rcp — accuracy-critical)
      const float ig = rcp(1.0f + ex2(a01.x));  // sig(i)
      const float fg = rcp(1.0f + ex2(a01.y));  // sig(f)
      const float rg = rcp(1.0f + ex2(a23.x));  // (1-tanh(g))/2
      const float og = rcp(1.0f + ex2(a23.y));  // sig(o)
      const float gg2 = fmaf(rg, -2.0f * G_SCALE, G_SCALE);  // 2log2e*tanh(g)
      // (ii) rebalance: fg*c2 overlaps gg2's fma
      const float fc = fg * c2;
      c2 = fmaf(ig, gg2, fc);
      const float rc = rcp(1.0f + ex2(c2));  // (1-tanh(c))/2
      const float m2og = -2.0f * og;         // off-chain
      h = fmaf(rc, m2og, og);                // og*tanh(c)
    };

    __syncthreads();

    for (int ck = 0; ck < NCHUNK; ++ck) {
      const float(*pa)[16][16] = (ck & 1) ? pa1 : pa0;
      const float* base = &pa[0][grp][j * 4];

      float4 ra[8], rb[8];
#define LOADB(r, u0)                                                \
  {                                                                 \
    _Pragma("unroll") for (int k = 0; k < 8; ++k) (r)[k] =          \
        *(const float4*)(base + (u0 + k) * 256);                    \
  }
#define COMP8(r)                                   \
  { _Pragma("unroll") for (int k = 0; k < 8; ++k) step((r)[k]); }

      LOADB(ra, 0)
      LOADB(rb, 8)
      COMP8(ra)
      LOADB(ra, 16)
      COMP8(rb)
      LOADB(rb, 24)
      COMP8(ra)
      COMP8(rb)
#undef LOADB
#undef COMP8
      __syncthreads();
    }

    // final FC: out[b] = sum_j h_j * fc_w[j] + fc_b
    float v = h * fc_w[j];
    v += dppf<0xB1>(v);  // quad_perm [1,0,3,2]
    v += dppf<0x4E>(v);  // quad_perm [2,3,0,1]
    if (j == 0 && b < B) out[b] = v + fc_b[0];
  }
}

extern "C" void kernel_launch(void* const* d_in, const int* in_sizes, int n_in,
                              void* d_out, int out_size, void* d_ws,
                              size_t ws_size, hipStream_t stream) {
  const float* x = (const float*)d_in[0];
  const float* W_ih = (const float*)d_in[1];
  const float* W_hh = (const float*)d_in[2];
  const float* b_ih = (const float*)d_in[3];
  const float* b_hh = (const float*)d_in[4];
  const float* fc_w = (const float*)d_in[5];
  const float* fc_b = (const float*)d_in[6];
  float* out = (float*)d_out;

  const int B = in_sizes[0] / (TT * II);
  const int nblocks = (B + 15) / 16;
  lstm_fused<<<nblocks, 128, 0, stream>>>(x, W_ih, W_hh, b_ih, b_hh, fc_w,
                                          fc_b, out, B);
}